// Round 3
// baseline (341.375 us; speedup 1.0000x reference)
//
#include <hip/hip_runtime.h>

#define WW   320
#define HH   160
#define CIN  80
#define COUT 32
#define DD   48
#define NB   8
#define VP   84   // fused-fallback vol row pad
#define VP2  68   // split K2 vol row pad (5 passes of 64)

typedef __bf16 bf16x8 __attribute__((ext_vector_type(8)));
typedef __bf16 bf16x4 __attribute__((ext_vector_type(4)));
typedef float  float4v __attribute__((ext_vector_type(4)));

// ============================================================================
// R4: SPLIT kernels. Rationale: fused structure is pinned at ~1.5 TB/s
// effective (24% of HBM) with all pipes idle -- barrier-ganged load bursts
// with only 2 blocks/CU leave the memory system unfed between gangs.
// K1 = R1's proven preconv (one image per block, 3 blocks/CU), dumps
// pre-swizzled bf16 features to workspace. K2 = verified R2 P2 banded
// volume (3 blocks/CU), reads features back (L2/L3-hot). Fused kernel kept
// as fallback if ws_size < 50 MB.
// ============================================================================

// ---------------- K1: preconv, one block per (img,b,h) ----------------
__global__ __launch_bounds__(320, 2)
void preconv_kernel(const float* __restrict__ inL, const float* __restrict__ inR,
                    const float* __restrict__ gamma, const float* __restrict__ beta,
                    const float* __restrict__ bnmean, const float* __restrict__ bnvar,
                    const float* __restrict__ convw, const float* __restrict__ convb,
                    __bf16* __restrict__ feat)   // [2*NB*HH] rows of 320*32 bf16
{
    __shared__ __align__(16) __bf16 xs2[WW * COUT];   // 20480 B staging
    __shared__ __align__(16) __bf16 fs [WW * COUT];   // 20480 B result row
    __shared__ __align__(16) float  scs[96];
    __shared__ float shs[80];
    __shared__ float biasp[32];
    __shared__ float scratch[320];

    const int t = threadIdx.x;         // == w
    const int idx = blockIdx.x;        // img*1280 + b*160 + h
    const int img = idx / (NB * HH);
    const int rem = idx - img * (NB * HH);
    const int b = rem / HH;
    const int h = rem % HH;
    const size_t HW = (size_t)HH * WW;
    const int wave = t >> 6, lane = t & 63, ln15 = lane & 15, quad = lane >> 4;
    const int w = t;
    const int sw = (w >> 1) & 3;

    // P0a: BN folds
    if (t < CIN) {
        float sc = gamma[t] * rsqrtf(bnvar[t] + 1e-5f);
        scs[t] = sc;
        shs[t] = fmaf(-bnmean[t], sc, beta[t]);
    } else if (t < 96) {
        scs[t] = 0.f;
    }
    __syncthreads();

    // P0b: weight A-frags (regs) + bias partials
    bf16x8 afr[2][3];
    #pragma unroll
    for (int mt = 0; mt < 2; ++mt) {
        #pragma unroll
        for (int kk = 0; kk < 3; ++kk) {
            const int c0 = kk * 32 + quad * 8;
            bf16x8 a;
            if (c0 < CIN) {
                const float* wp = convw + (mt * 16 + ln15) * CIN + c0;
                float4v w0 = *(const float4v*)wp;
                float4v w1 = *(const float4v*)(wp + 4);
                float4v s0 = *(const float4v*)(scs + c0);
                float4v s1 = *(const float4v*)(scs + c0 + 4);
                #pragma unroll
                for (int j = 0; j < 4; ++j) {
                    a[j]     = (__bf16)(w0[j] * s0[j]);
                    a[j + 4] = (__bf16)(w1[j] * s1[j]);
                }
            } else {
                #pragma unroll
                for (int j = 0; j < 8; ++j) a[j] = (__bf16)0.f;
            }
            afr[mt][kk] = a;
        }
    }
    {
        const int o = t & 31, part = t >> 5;
        float p = 0.f;
        #pragma unroll
        for (int j = 0; j < 8; ++j) {
            int c = part * 8 + j;
            p = fmaf(shs[c], convw[o * CIN + c], p);
        }
        scratch[part * 32 + o] = p;
    }
    __syncthreads();
    if (t < 32) {
        float s = convb[t];
        #pragma unroll
        for (int pt = 0; pt < 10; ++pt) s += scratch[pt * 32 + t];
        biasp[t] = s;   // visible after next barrier (inside P1)
    }

    // P1: preconv via MFMA (R1 structure, single image)
    const float* __restrict__ px =
        (img ? inR : inL) + ((size_t)b * CIN * HH + h) * WW + w;

    float4v acc[2][4];
    #pragma unroll
    for (int mt = 0; mt < 2; ++mt)
        #pragma unroll
        for (int nn = 0; nn < 4; ++nn) acc[mt][nn] = (float4v){0.f, 0.f, 0.f, 0.f};

    float y[32];
    #pragma unroll
    for (int u = 0; u < 32; ++u) y[u] = px[(size_t)u * HW];
    #pragma unroll
    for (int g = 0; g < 4; ++g) {
        bf16x8 pk;
        #pragma unroll
        for (int j = 0; j < 8; ++j) pk[j] = (__bf16)fmaxf(y[g * 8 + j], 0.f);
        *(bf16x8*)(xs2 + w * 32 + ((g ^ sw) << 3)) = pk;
    }
    __syncthreads();

    #pragma unroll
    for (int kk = 0; kk < 3; ++kk) {
        if (kk < 2) {
            #pragma unroll
            for (int u = 0; u < 32; ++u) {
                int c = (kk + 1) * 32 + u;
                y[u] = (c < CIN) ? px[(size_t)c * HW] : 0.f;
            }
        }
        #pragma unroll
        for (int nn = 0; nn < 4; ++nn) {
            const int wr = (nn * 5 + wave) * 16 + ln15;
            bf16x8 bv = *(const bf16x8*)(xs2 + wr * 32 +
                                         ((quad ^ ((wr >> 1) & 3)) << 3));
            acc[0][nn] = __builtin_amdgcn_mfma_f32_16x16x32_bf16(afr[0][kk], bv, acc[0][nn], 0, 0, 0);
            acc[1][nn] = __builtin_amdgcn_mfma_f32_16x16x32_bf16(afr[1][kk], bv, acc[1][nn], 0, 0, 0);
        }
        __syncthreads();
        if (kk < 2) {
            #pragma unroll
            for (int g = 0; g < 4; ++g) {
                bf16x8 pk;
                #pragma unroll
                for (int j = 0; j < 8; ++j) pk[j] = (__bf16)fmaxf(y[g * 8 + j], 0.f);
                *(bf16x8*)(xs2 + w * 32 + ((g ^ sw) << 3)) = pk;
            }
            __syncthreads();
        }
    }

    // epilogue: D (+bias) -> fs bf16 [w][o], swizzled (same layout as fused)
    #pragma unroll
    for (int nn = 0; nn < 4; ++nn) {
        const int wg  = (nn * 5 + wave) * 16 + ln15;
        const int swg = (wg >> 1) & 3;
        #pragma unroll
        for (int mt = 0; mt < 2; ++mt) {
            float4v bi = *(const float4v*)(biasp + mt * 16 + quad * 4);
            bf16x4 o4;
            #pragma unroll
            for (int r = 0; r < 4; ++r)
                o4[r] = (__bf16)(acc[mt][nn][r] + bi[r]);
            const int g = 2 * mt + (quad >> 1);
            *(bf16x4*)(fs + wg * 32 + ((g ^ swg) << 3) + (quad & 1) * 4) = o4;
        }
    }
    __syncthreads();

    // dump pre-swizzled row to workspace, fully coalesced float4
    {
        const float4v* src = (const float4v*)fs;            // 1280 x 16 B
        float4v* dst = (float4v*)(feat + (size_t)idx * (WW * COUT));
        for (int s = t; s < (WW * COUT * 2) / 16; s += 320) dst[s] = src[s];
    }
}

// ---------------- K2: banded volume, one block per (b,h) ----------------
__global__ __launch_bounds__(320, 2)
void volume_kernel(const __bf16* __restrict__ feat, float* __restrict__ out)
{
    __shared__ __align__(16) __bf16 fLs[WW * COUT];   // 20480 B
    __shared__ __align__(16) __bf16 fRs[WW * COUT];   // 20480 B
    __shared__ __align__(16) float  vol[DD * VP2];    // 13056 B
    // total 54016 B -> 3 blocks/CU

    const int t = threadIdx.x;
    const int bh = blockIdx.x;
    const int b = bh / HH;
    const int h = bh % HH;
    const int wave = t >> 6, lane = t & 63, ln15 = lane & 15, quad = lane >> 4;

    // load both feature rows (pre-swizzled) -- coalesced float4
    {
        const float4v* srcL = (const float4v*)(feat + (size_t)bh * (WW * COUT));
        const float4v* srcR = (const float4v*)(feat + (size_t)(NB * HH + bh) * (WW * COUT));
        float4v* dL = (float4v*)fLs;
        float4v* dR = (float4v*)fRs;
        for (int s = t; s < (WW * COUT * 2) / 16; s += 320) {
            dL[s] = srcL[s];
            dR[s] = srcR[s];
        }
    }
    __syncthreads();

    // P2: banded volume via MFMA, 5 passes of 64 w (verified in R2)
    #pragma unroll 1
    for (int pass = 0; pass < 5; ++pass) {
        for (int k = wave; k < 16; k += 5) {
            const int two = k >> 2;            // w-tile within pass: 0..3
            const int d   = k & 3;             // j-tile lag: 0..3
            const int tw  = pass * 4 + two;
            const int tj  = tw - d;
            if (tj >= 0) {
                const int wr = tw * 16 + ln15;
                const int jr = tj * 16 + ln15;
                bf16x8 av = *(const bf16x8*)(fLs + wr * 32 +
                                             ((quad ^ ((wr >> 1) & 3)) << 3));
                bf16x8 bv = *(const bf16x8*)(fRs + jr * 32 +
                                             ((quad ^ ((jr >> 1) & 3)) << 3));
                float4v cz = {0.f, 0.f, 0.f, 0.f};
                float4v dv = __builtin_amdgcn_mfma_f32_16x16x32_bf16(av, bv, cz, 0, 0, 0);
                #pragma unroll
                for (int r = 0; r < 4; ++r) {
                    int row = quad * 4 + r;
                    int i = 16 * d + row - ln15;   // disparity
                    if (i >= 0 && i < DD)
                        vol[i * VP2 + two * 16 + row] = dv[r] * (1.f / 32.f);
                }
            }
        }
        __syncthreads();

        // coalesced float4 store of 48 x 64 chunk; w<i band forced to 0
        for (int s = t; s < DD * 16; s += 320) {
            int i = s >> 4, q = s & 15;
            int w0 = pass * 64 + q * 4;
            float4v v = *(const float4v*)(vol + i * VP2 + q * 4);
            #pragma unroll
            for (int e = 0; e < 4; ++e)
                if (w0 + e < i) v[e] = 0.f;
            *(float4v*)(out + ((size_t)(b * DD + i) * HH + h) * WW + w0) = v;
        }
        __syncthreads();
    }
}

// ---------------- Fused fallback (R3, proven 140 us/dispatch) ----------------
__global__ __launch_bounds__(320, 2)
void vol_kernel(const float* __restrict__ inL, const float* __restrict__ inR,
                const float* __restrict__ gamma, const float* __restrict__ beta,
                const float* __restrict__ bnmean, const float* __restrict__ bnvar,
                const float* __restrict__ convw, const float* __restrict__ convb,
                float* __restrict__ out)
{
    __shared__ __align__(16) __bf16 fLs[WW * COUT];
    __shared__ __align__(16) __bf16 fRs[WW * COUT];
    __shared__ __align__(16) char   uni[WW * COUT * 2];
    __shared__ __align__(16) float  scs[96];
    __shared__ float  shs[80];
    __shared__ float  biasp[32];
    __shared__ float  scratch[320];

    __bf16* xs2 = (__bf16*)uni;
    float*  vol = (float*)uni;

    const int t = threadIdx.x;
    const int b = blockIdx.x / HH;
    const int h = blockIdx.x % HH;
    const size_t HW = (size_t)HH * WW;
    const int wave = t >> 6, lane = t & 63, ln15 = lane & 15, quad = lane >> 4;
    const int w = t;
    const int sw = (w >> 1) & 3;

    if (t < CIN) {
        float sc = gamma[t] * rsqrtf(bnvar[t] + 1e-5f);
        scs[t] = sc;
        shs[t] = fmaf(-bnmean[t], sc, beta[t]);
    } else if (t < 96) {
        scs[t] = 0.f;
    }
    __syncthreads();

    bf16x8 afr[2][3];
    #pragma unroll
    for (int mt = 0; mt < 2; ++mt) {
        #pragma unroll
        for (int kk = 0; kk < 3; ++kk) {
            const int c0 = kk * 32 + quad * 8;
            bf16x8 a;
            if (c0 < CIN) {
                const float* wp = convw + (mt * 16 + ln15) * CIN + c0;
                float4v w0 = *(const float4v*)wp;
                float4v w1 = *(const float4v*)(wp + 4);
                float4v s0 = *(const float4v*)(scs + c0);
                float4v s1 = *(const float4v*)(scs + c0 + 4);
                #pragma unroll
                for (int j = 0; j < 4; ++j) {
                    a[j]     = (__bf16)(w0[j] * s0[j]);
                    a[j + 4] = (__bf16)(w1[j] * s1[j]);
                }
            } else {
                #pragma unroll
                for (int j = 0; j < 8; ++j) a[j] = (__bf16)0.f;
            }
            afr[mt][kk] = a;
        }
    }
    {
        const int o = t & 31, part = t >> 5;
        float p = 0.f;
        #pragma unroll
        for (int j = 0; j < 8; ++j) {
            int c = part * 8 + j;
            p = fmaf(shs[c], convw[o * CIN + c], p);
        }
        scratch[part * 32 + o] = p;
    }
    __syncthreads();
    if (t < 32) {
        float s = convb[t];
        #pragma unroll
        for (int pt = 0; pt < 10; ++pt) s += scratch[pt * 32 + t];
        biasp[t] = s;
    }

    #pragma unroll 1
    for (int img = 0; img < 2; ++img) {
        const float* __restrict__ px =
            (img ? inR : inL) + ((size_t)b * CIN * HH + h) * WW + w;
        __bf16* f = img ? fRs : fLs;

        float4v acc[2][4];
        #pragma unroll
        for (int mt = 0; mt < 2; ++mt)
            #pragma unroll
            for (int nn = 0; nn < 4; ++nn) acc[mt][nn] = (float4v){0.f, 0.f, 0.f, 0.f};

        float y[32];
        #pragma unroll
        for (int u = 0; u < 32; ++u) y[u] = px[(size_t)u * HW];
        #pragma unroll
        for (int g = 0; g < 4; ++g) {
            bf16x8 pk;
            #pragma unroll
            for (int j = 0; j < 8; ++j) pk[j] = (__bf16)fmaxf(y[g * 8 + j], 0.f);
            *(bf16x8*)(xs2 + w * 32 + ((g ^ sw) << 3)) = pk;
        }
        __syncthreads();

        #pragma unroll
        for (int kk = 0; kk < 3; ++kk) {
            if (kk < 2) {
                #pragma unroll
                for (int u = 0; u < 32; ++u) {
                    int c = (kk + 1) * 32 + u;
                    y[u] = (c < CIN) ? px[(size_t)c * HW] : 0.f;
                }
            }
            #pragma unroll
            for (int nn = 0; nn < 4; ++nn) {
                const int wr = (nn * 5 + wave) * 16 + ln15;
                bf16x8 bv = *(const bf16x8*)(xs2 + wr * 32 +
                                             ((quad ^ ((wr >> 1) & 3)) << 3));
                acc[0][nn] = __builtin_amdgcn_mfma_f32_16x16x32_bf16(afr[0][kk], bv, acc[0][nn], 0, 0, 0);
                acc[1][nn] = __builtin_amdgcn_mfma_f32_16x16x32_bf16(afr[1][kk], bv, acc[1][nn], 0, 0, 0);
            }
            __syncthreads();
            if (kk < 2) {
                #pragma unroll
                for (int g = 0; g < 4; ++g) {
                    bf16x8 pk;
                    #pragma unroll
                    for (int j = 0; j < 8; ++j) pk[j] = (__bf16)fmaxf(y[g * 8 + j], 0.f);
                    *(bf16x8*)(xs2 + w * 32 + ((g ^ sw) << 3)) = pk;
                }
                __syncthreads();
            }
        }

        #pragma unroll
        for (int nn = 0; nn < 4; ++nn) {
            const int wg  = (nn * 5 + wave) * 16 + ln15;
            const int swg = (wg >> 1) & 3;
            #pragma unroll
            for (int mt = 0; mt < 2; ++mt) {
                float4v bi = *(const float4v*)(biasp + mt * 16 + quad * 4);
                bf16x4 o4;
                #pragma unroll
                for (int r = 0; r < 4; ++r)
                    o4[r] = (__bf16)(acc[mt][nn][r] + bi[r]);
                const int g = 2 * mt + (quad >> 1);
                *(bf16x4*)(f + wg * 32 + ((g ^ swg) << 3) + (quad & 1) * 4) = o4;
            }
        }
    }
    __syncthreads();

    for (int pass = 0; pass < 4; ++pass) {
        for (int k = wave; k < 20; k += 5) {
            const int two = k >> 2;
            const int d   = k & 3;
            const int tw  = pass * 5 + two;
            const int tj  = tw - d;
            if (tj >= 0) {
                const int wr = tw * 16 + ln15;
                const int jr = tj * 16 + ln15;
                bf16x8 av = *(const bf16x8*)(fLs + wr * 32 +
                                             ((quad ^ ((wr >> 1) & 3)) << 3));
                bf16x8 bv = *(const bf16x8*)(fRs + jr * 32 +
                                             ((quad ^ ((jr >> 1) & 3)) << 3));
                float4v cz = {0.f, 0.f, 0.f, 0.f};
                float4v dv = __builtin_amdgcn_mfma_f32_16x16x32_bf16(av, bv, cz, 0, 0, 0);
                #pragma unroll
                for (int r = 0; r < 4; ++r) {
                    int row = quad * 4 + r;
                    int i = 16 * d + row - ln15;
                    if (i >= 0 && i < DD)
                        vol[i * VP + two * 16 + row] = dv[r] * (1.f / 32.f);
                }
            }
        }
        __syncthreads();

        for (int s = t; s < DD * 20; s += 320) {
            int i = s / 20, q = s - i * 20;
            int wg0 = pass * 80 + q * 4;
            float4v v = *(const float4v*)(vol + i * VP + q * 4);
            #pragma unroll
            for (int e = 0; e < 4; ++e)
                if (wg0 + e < i) v[e] = 0.f;
            *(float4v*)(out + ((size_t)(b * DD + i) * HH + h) * WW + wg0) = v;
        }
        __syncthreads();
    }
}

extern "C" void kernel_launch(void* const* d_in, const int* in_sizes, int n_in,
                              void* d_out, int out_size, void* d_ws, size_t ws_size,
                              hipStream_t stream) {
    const float* inL    = (const float*)d_in[0];
    const float* inR    = (const float*)d_in[1];
    const float* gamma  = (const float*)d_in[2];
    const float* beta   = (const float*)d_in[3];
    const float* bnmean = (const float*)d_in[4];
    const float* bnvar  = (const float*)d_in[5];
    const float* convw  = (const float*)d_in[6];
    const float* convb  = (const float*)d_in[7];
    float* out = (float*)d_out;

    const size_t need = (size_t)2 * NB * HH * WW * COUT * sizeof(__bf16); // 50 MB

    if (d_ws != nullptr && ws_size >= need) {
        __bf16* feat = (__bf16*)d_ws;
        preconv_kernel<<<dim3(2 * NB * HH), dim3(320), 0, stream>>>(
            inL, inR, gamma, beta, bnmean, bnvar, convw, convb, feat);
        volume_kernel<<<dim3(NB * HH), dim3(320), 0, stream>>>(feat, out);
    } else {
        vol_kernel<<<dim3(NB * HH), dim3(320), 0, stream>>>(
            inL, inR, gamma, beta, bnmean, bnvar, convw, convb, out);
    }
}

// Round 4
// 333.583 us; speedup vs baseline: 1.0234x; 1.0234x over previous
//
#include <hip/hip_runtime.h>

#define WW   320
#define HH   160
#define CIN  80
#define COUT 32
#define DD   48
#define NB   8
#define VP   84   // vol row pad (f32 words)

typedef __bf16 bf16x8 __attribute__((ext_vector_type(8)));
typedef __bf16 bf16x4 __attribute__((ext_vector_type(4)));
typedef float  float4v __attribute__((ext_vector_type(4)));

// One block per (b,h) row; 320 threads, 5 waves.
// R5 = R3 fused base + VECTORIZED input reads (the one change).
// Theory: every prior round was pinned at ~2.5-2.8 TB/s logical = the known
// scalar-4B-load ceiling (m18: 2.35 TB/s scalar vs m146: 4.89 TB/s vec).
// New read: thread t -> (tq=t/80, w4=t%80); per chunk of 32 channels,
// 8 float4 loads (4 channel-rows x 1280 B per step, 16 B/lane coalesced),
// then scatter-pack 32 bf16 into xs2 [w][32c] with XOR key (w>>2)&3
// (uniform per thread). Frag reads use the same key. MFMA/epilogue/P2
// and the fLs/fRs swizzle (key (w>>1)&3) untouched. NT stores kept (R3).
__global__ __launch_bounds__(320, 2)
void vol_kernel(const float* __restrict__ inL, const float* __restrict__ inR,
                const float* __restrict__ gamma, const float* __restrict__ beta,
                const float* __restrict__ bnmean, const float* __restrict__ bnvar,
                const float* __restrict__ convw, const float* __restrict__ convb,
                float* __restrict__ out)
{
    __shared__ __align__(16) __bf16 fLs[WW * COUT];       // 20480 B
    __shared__ __align__(16) __bf16 fRs[WW * COUT];       // 20480 B
    __shared__ __align__(16) char   uni[WW * COUT * 2];   // 20480 B: xs2 | vol
    __shared__ __align__(16) float  scs[96];              // sc (zero-pad 80..95)
    __shared__ float  shs[80];
    __shared__ float  biasp[32];
    __shared__ float  scratch[320];

    __bf16* xs2 = (__bf16*)uni;        // [320][32] bf16, swizzled key (w>>2)&3
    float*  vol = (float*)uni;         // [48][84] f32 (phase 2 only)

    const int t = threadIdx.x;
    const int b = blockIdx.x / HH;
    const int h = blockIdx.x % HH;
    const size_t HW = (size_t)HH * WW;
    const int wave = t >> 6, lane = t & 63, ln15 = lane & 15, quad = lane >> 4;
    const int tq = t / 80;             // channel sub-index within 4-group
    const int w4 = t - tq * 80;        // float4 index along w (0..79)

    // ---------------- P0a: BN folds ----------------
    if (t < CIN) {
        float sc = gamma[t] * rsqrtf(bnvar[t] + 1e-5f);
        scs[t] = sc;
        shs[t] = fmaf(-bnmean[t], sc, beta[t]);
    } else if (t < 96) {
        scs[t] = 0.f;
    }
    __syncthreads();

    // ---------------- P0b: weight A-frags (regs) + bias partials ----------
    bf16x8 afr[2][3];   // [m-tile][k-chunk]; A[m=o][k=c] = W[o][c]*sc_c
    #pragma unroll
    for (int mt = 0; mt < 2; ++mt) {
        #pragma unroll
        for (int kk = 0; kk < 3; ++kk) {
            const int c0 = kk * 32 + quad * 8;
            bf16x8 a;
            if (c0 < CIN) {           // c0 multiple of 8; 80-c0 too -> no straddle
                const float* wp = convw + (mt * 16 + ln15) * CIN + c0;
                float4v w0 = *(const float4v*)wp;
                float4v w1 = *(const float4v*)(wp + 4);
                float4v s0 = *(const float4v*)(scs + c0);
                float4v s1 = *(const float4v*)(scs + c0 + 4);
                #pragma unroll
                for (int j = 0; j < 4; ++j) {
                    a[j]     = (__bf16)(w0[j] * s0[j]);
                    a[j + 4] = (__bf16)(w1[j] * s1[j]);
                }
            } else {
                #pragma unroll
                for (int j = 0; j < 8; ++j) a[j] = (__bf16)0.f;
            }
            afr[mt][kk] = a;
        }
    }
    {   // bias partials: thread (o=t&31, part=t>>5) does 8 FMAs
        const int o = t & 31, part = t >> 5;
        float p = 0.f;
        #pragma unroll
        for (int j = 0; j < 8; ++j) {
            int c = part * 8 + j;
            p = fmaf(shs[c], convw[o * CIN + c], p);
        }
        scratch[part * 32 + o] = p;
    }
    __syncthreads();
    if (t < 32) {
        float s = convb[t];
        #pragma unroll
        for (int pt = 0; pt < 10; ++pt) s += scratch[pt * 32 + t];
        biasp[t] = s;   // visible to all after next barrier (inside P1)
    }

    // ---------------- P1: preconv via MFMA, per image ----------------
    #pragma unroll 1
    for (int img = 0; img < 2; ++img) {
        const float* __restrict__ pimg =
            (img ? inR : inL) + ((size_t)b * CIN * HH + h) * WW;
        __bf16* f = img ? fRs : fLs;

        float4v acc[2][4];
        #pragma unroll
        for (int mt = 0; mt < 2; ++mt)
            #pragma unroll
            for (int nn = 0; nn < 4; ++nn) acc[mt][nn] = (float4v){0.f, 0.f, 0.f, 0.f};

        float4v y4[8];   // one 32-channel chunk: 8 steps x 4 channels (float4/lane)

        // stage chunk 0 (c = s*4+tq < 32, no guard needed)
        #pragma unroll
        for (int s = 0; s < 8; ++s)
            y4[s] = *(const float4v*)(pimg + (size_t)(s * 4 + tq) * HW + w4 * 4);
        #pragma unroll
        for (int s = 0; s < 8; ++s) {
            const int csub = s * 4 + tq;
            const int oc = (((csub >> 3) ^ (w4 & 3)) << 3) + (csub & 7);
            #pragma unroll
            for (int j = 0; j < 4; ++j)
                xs2[(w4 * 4 + j) * 32 + oc] = (__bf16)fmaxf(y4[s][j], 0.f);
        }
        __syncthreads();

        #pragma unroll
        for (int kk = 0; kk < 3; ++kk) {
            if (kk < 2) {               // prefetch chunk kk+1 (regs, overlaps MFMA)
                #pragma unroll
                for (int s = 0; s < 8; ++s) {
                    const int c = (kk + 1) * 32 + s * 4 + tq;
                    y4[s] = (c < CIN)
                        ? *(const float4v*)(pimg + (size_t)c * HW + w4 * 4)
                        : (float4v){0.f, 0.f, 0.f, 0.f};
                }
            }
            #pragma unroll
            for (int nn = 0; nn < 4; ++nn) {
                const int wr = (nn * 5 + wave) * 16 + ln15;   // n = w
                bf16x8 bv = *(const bf16x8*)(xs2 + wr * 32 +
                                             ((quad ^ ((wr >> 2) & 3)) << 3));
                acc[0][nn] = __builtin_amdgcn_mfma_f32_16x16x32_bf16(afr[0][kk], bv, acc[0][nn], 0, 0, 0);
                acc[1][nn] = __builtin_amdgcn_mfma_f32_16x16x32_bf16(afr[1][kk], bv, acc[1][nn], 0, 0, 0);
            }
            __syncthreads();            // all reads of xs2 done
            if (kk < 2) {
                #pragma unroll
                for (int s = 0; s < 8; ++s) {
                    const int csub = s * 4 + tq;
                    const int oc = (((csub >> 3) ^ (w4 & 3)) << 3) + (csub & 7);
                    #pragma unroll
                    for (int j = 0; j < 4; ++j)
                        xs2[(w4 * 4 + j) * 32 + oc] = (__bf16)fmaxf(y4[s][j], 0.f);
                }
                __syncthreads();        // staged for next iter
            }
        }

        // D (+bias) -> f bf16 [w][o], swizzled. D: row(m=o)=quad*4+r, col(n=w)=ln15
        #pragma unroll
        for (int nn = 0; nn < 4; ++nn) {
            const int wg  = (nn * 5 + wave) * 16 + ln15;
            const int swg = (wg >> 1) & 3;
            #pragma unroll
            for (int mt = 0; mt < 2; ++mt) {
                float4v bi = *(const float4v*)(biasp + mt * 16 + quad * 4);
                bf16x4 o4;
                #pragma unroll
                for (int r = 0; r < 4; ++r)
                    o4[r] = (__bf16)(acc[mt][nn][r] + bi[r]);
                const int g = 2 * mt + (quad >> 1);
                *(bf16x4*)(f + wg * 32 + ((g ^ swg) << 3) + (quad & 1) * 4) = o4;
            }
        }
    }
    __syncthreads();

    // ---------------- P2: banded volume via MFMA (unchanged) ----------------
    for (int pass = 0; pass < 4; ++pass) {
        for (int k = wave; k < 20; k += 5) {
            const int two = k >> 2;            // w-tile within pass: 0..4
            const int d   = k & 3;             // j-tile lag: 0..3
            const int tw  = pass * 5 + two;
            const int tj  = tw - d;
            if (tj >= 0) {
                const int wr = tw * 16 + ln15;  // A row (w)
                const int jr = tj * 16 + ln15;  // B row (j)
                bf16x8 av = *(const bf16x8*)(fLs + wr * 32 +
                                             ((quad ^ ((wr >> 1) & 3)) << 3));
                bf16x8 bv = *(const bf16x8*)(fRs + jr * 32 +
                                             ((quad ^ ((jr >> 1) & 3)) << 3));
                float4v cz = {0.f, 0.f, 0.f, 0.f};
                float4v dv = __builtin_amdgcn_mfma_f32_16x16x32_bf16(av, bv, cz, 0, 0, 0);
                #pragma unroll
                for (int r = 0; r < 4; ++r) {
                    int row = quad * 4 + r;
                    int i = 16 * d + row - ln15;   // disparity
                    if (i >= 0 && i < DD)
                        vol[i * VP + two * 16 + row] = dv[r] * (1.f / 32.f);
                }
            }
        }
        __syncthreads();

        // coalesced float4 NON-TEMPORAL store of 48 x 80 chunk; w<i band -> 0
        for (int s = t; s < DD * 20; s += 320) {
            int i = s / 20, q = s - i * 20;
            int wg0 = pass * 80 + q * 4;
            float4v v = *(const float4v*)(vol + i * VP + q * 4);
            #pragma unroll
            for (int e = 0; e < 4; ++e)
                if (wg0 + e < i) v[e] = 0.f;
            __builtin_nontemporal_store(
                v, (float4v*)(out + ((size_t)(b * DD + i) * HH + h) * WW + wg0));
        }
        __syncthreads();
    }
}

extern "C" void kernel_launch(void* const* d_in, const int* in_sizes, int n_in,
                              void* d_out, int out_size, void* d_ws, size_t ws_size,
                              hipStream_t stream) {
    const float* inL    = (const float*)d_in[0];
    const float* inR    = (const float*)d_in[1];
    const float* gamma  = (const float*)d_in[2];
    const float* beta   = (const float*)d_in[3];
    const float* bnmean = (const float*)d_in[4];
    const float* bnvar  = (const float*)d_in[5];
    const float* convw  = (const float*)d_in[6];
    const float* convb  = (const float*)d_in[7];
    float* out = (float*)d_out;

    dim3 grid(NB * HH);   // 1280 row-blocks
    dim3 block(320);
    vol_kernel<<<grid, block, 0, stream>>>(inL, inR, gamma, beta, bnmean, bnvar,
                                           convw, convb, out);
}